// Round 1
// 5468.898 us; speedup vs baseline: 1.2677x; 1.2677x over previous
//
#include <hip/hip_runtime.h>
#include <hip/hip_bf16.h>

// ---------------------------------------------------------------------------
// LSTM: T=256, B=128, F=1024, H=1024.  gates = [x_t | h] @ [W_ih; W_hh] + bias
// Persistent kernel, 256 WGs. Swizzled mapping: r=(wg>>3)&3 (32-row group),
// j=(wg&7)*8+(wg>>5) (16-col group). Wave = gate. bf16 MFMA 16x16x32.
//
// R4 changes vs R3 (26.2 us/step, MfmaUtil 3.3% -> latency-bound):
//  - ALL B-fragments (K=2048, 64 frags x 16B/lane = 256 VGPRs) live in
//    registers, loaded ONCE before the t-loop. The per-step agent acquire
//    fences invalidate the XCD L2 every step (32x/XCD/step), so streamed
//    weight loads were served from IF at ~800cy; registers are immune.
//    Requires __launch_bounds__(256,1): 1 wave/SIMD (already the occupancy),
//    512-VGPR budget.
//  - Full-K LDS staging (64 KiB Abuf) instead of 2x 32 KiB chunks: 5
//    __syncthreads per step instead of ~10.
//  - Tier-D strided-fp32 fallback (bfrag_f32 / wcut) is dead: registers are
//    loaded at t=-1, before any out-row >= 224 is overwritten (t=224 needs
//    224 sync rounds first). Uniform fast path for all t.
//  - Sync protocol (spread sub-counters + per-row-group aggregator +
//    release flag) unchanged from R3 -- proven correct.
// Workspace tiers (never write past ws_size):
//    counters(16K) | pB(16M) | pH(512K) | pX(64M), each only if it fits;
//    tier D: pB packed into out rows [224,256).
// ---------------------------------------------------------------------------

typedef __attribute__((ext_vector_type(8))) short short8;   // 8 bf16 = 4 VGPRs
typedef __attribute__((ext_vector_type(4))) float floatx4;  // MFMA accumulator

#define HID_OFF 33554432L   // T*B*H
#define CT_OFF  33685504L   // T*B*H + B*H
#define WTAIL_F 29360128L   // 224*131072 : float offset of hid rows [224,256)

__device__ __forceinline__ unsigned short f2bf(float f) {
    __hip_bfloat16 hb = __float2bfloat16(f);
    return *reinterpret_cast<unsigned short*>(&hb);
}

// 8 contiguous fp32 -> 8 bf16 packed in a uint4
__device__ __forceinline__ uint4 pack8(const float* p) {
    float4 f0 = *reinterpret_cast<const float4*>(p);
    float4 f1 = *reinterpret_cast<const float4*>(p + 4);
    union { uint4 v; unsigned short u[8]; } t;
    t.u[0] = f2bf(f0.x); t.u[1] = f2bf(f0.y); t.u[2] = f2bf(f0.z); t.u[3] = f2bf(f0.w);
    t.u[4] = f2bf(f1.x); t.u[5] = f2bf(f1.y); t.u[6] = f2bf(f1.z); t.u[7] = f2bf(f1.w);
    return t.v;
}

// ---- pack weights into B-fragment order: frag=(nblk*64+kblk), lane, 8 bf16 ----
__global__ void pack_w_kernel(const float* __restrict__ wih,
                              const float* __restrict__ whh,
                              unsigned short* __restrict__ pB) {
    int g    = blockIdx.x * 256 + threadIdx.x;   // 1,048,576 threads
    int lane = g & 63;
    int frag = g >> 6;
    int kblk = frag & 63;
    int nblk = frag >> 6;
    int n = nblk * 16 + (lane & 15);
    int k = kblk * 32 + ((lane >> 4) << 3);
    const float* src = (k < 1024) ? (wih + (size_t)k * 4096 + n)
                                  : (whh + (size_t)(k - 1024) * 4096 + n);
    __attribute__((aligned(16))) unsigned short tmp[8];
#pragma unroll
    for (int jj = 0; jj < 8; ++jj) tmp[jj] = f2bf(src[(size_t)jj * 4096]);
    *reinterpret_cast<uint4*>(pB + (size_t)frag * 512 + lane * 8) =
        *reinterpret_cast<const uint4*>(tmp);
}

// ---- pack x into A-fragment order: frag=(t*256 + mblk*32 + kblk) ----
__global__ void pack_x_kernel(const float* __restrict__ x,
                              unsigned short* __restrict__ pX) {
    int g    = blockIdx.x * 256 + threadIdx.x;   // 4,194,304 threads
    int lane = g & 63;
    int frag = g >> 6;
    int kblk = frag & 31;
    int mblk = (frag >> 5) & 7;
    int t    = frag >> 8;
    int m = mblk * 16 + (lane & 15);
    int k = kblk * 32 + ((lane >> 4) << 3);
    *reinterpret_cast<uint4*>(pX + (size_t)frag * 512 + lane * 8) =
        pack8(x + (size_t)(t * 128 + m) * 1024 + k);
}

// ---- init packed h0 (broadcast over batch rows) ----
__global__ void pack_h0_kernel(const float* __restrict__ h0,
                               unsigned short* __restrict__ pH) {
    int g    = blockIdx.x * 256 + threadIdx.x;   // 16,384 threads
    int lane = g & 63;
    int frag = g >> 6;            // mblk*32 + kblk
    int kblk = frag & 31;
    int k = kblk * 32 + ((lane >> 4) << 3);
    __attribute__((aligned(16))) unsigned short tmp[8];
#pragma unroll
    for (int jj = 0; jj < 8; ++jj) tmp[jj] = f2bf(h0[k + jj]);
    *reinterpret_cast<uint4*>(pH + (size_t)frag * 512 + lane * 8) =
        *reinterpret_cast<const uint4*>(tmp);
}

// ---- main persistent LSTM kernel ----
__global__ __launch_bounds__(256, 1) void lstm_main(
    const float* __restrict__ x, const float* __restrict__ h0,
    const float* __restrict__ c0, const float* __restrict__ bias,
    const unsigned short* __restrict__ pB,
    unsigned short* pH, int use_ph,
    const unsigned short* __restrict__ pX, int use_px,
    float* out, int* cnt) {

    __shared__ __align__(16) unsigned short Abuf[2][32][512];   // 64 KiB full-K A
    __shared__ float g_lds[4][32][17];                          // activated gates
    __shared__ float c_lds[32][16];                             // fp32 cell state
    __shared__ __align__(16) unsigned short hbf_lds[32][16];    // bf16 h staging

    const int tid  = threadIdx.x;
    const int lane = tid & 63;
    const int w    = tid >> 6;                 // wave index == gate (i,f,g,o)
    const int wg   = blockIdx.x;
    const int r    = (wg >> 3) & 3;            // row group (32 batch rows)
    const int j    = (wg & 7) * 8 + (wg >> 5); // h-col block (16 cols), XCD-swizzled
    const int col  = lane & 15;
    const int quad = lane >> 4;
    const int nblk = w * 64 + j;

    int* subp = cnt + (r * 8 + (j >> 3)) * 64;  // arrival sub-counter (256B spread)
    int* relp = cnt + (32 + r) * 64;            // release flag for row group
    const bool is_agg = (j == 0);

    const float breg = bias[w * 1024 + j * 16 + col];

    { // init cell state (broadcast c0 over batch rows)
        float cv = c0[j * 16 + (tid & 15)];
        int row = tid >> 4;
        c_lds[row][tid & 15]      = cv;
        c_lds[row + 16][tid & 15] = cv;
    }

    // ---- resident weights: all 64 B-fragments (x-half kb 0..31, h-half 32..63)
    // Loaded once; registers survive the per-step L2 invalidations. All indices
    // are compile-time after unroll -> stays in VGPRs (no scratch).
    const unsigned short* pBw = pB + (size_t)nblk * 64 * 512 + lane * 8;
    short8 bw[64];
#pragma unroll
    for (int kb = 0; kb < 64; ++kb)
        bw[kb] = *reinterpret_cast<const short8*>(pBw + (size_t)kb * 512);

    // ---- helpers -----------------------------------------------------------
    auto stage_x_full = [&](int tt) {
#pragma unroll
        for (int i = 0; i < 16; ++i) {
            int s = tid + 256 * i;                 // slot in [0,4096)
            int ln = s & 63, kbg = (s >> 6) & 31, mb = s >> 11;
            if (use_px) {
                const unsigned short* src =
                    pX + (((size_t)(tt * 8 + 2 * r + mb) * 32 + kbg) * 512) + ln * 8;
                *reinterpret_cast<uint4*>(&Abuf[mb][kbg][ln * 8]) =
                    *reinterpret_cast<const uint4*>(src);
            } else {
                int m = 32 * r + mb * 16 + (ln & 15);
                int k = kbg * 32 + ((ln >> 4) << 3);
                *reinterpret_cast<uint4*>(&Abuf[mb][kbg][ln * 8]) =
                    pack8(x + (size_t)(tt * 128 + m) * 1024 + k);
            }
        }
    };

    auto stage_h_full = [&](int tt) {
#pragma unroll
        for (int i = 0; i < 16; ++i) {
            int s = tid + 256 * i;
            int ln = s & 63, kbg = (s >> 6) & 31, mb = s >> 11;
            if (use_ph) {
                const unsigned short* src = pH + (size_t)(tt & 1) * 131072 +
                    (((size_t)(2 * r + mb) * 32 + kbg) * 512) + ln * 8;
                *reinterpret_cast<uint4*>(&Abuf[mb][kbg][ln * 8]) =
                    *reinterpret_cast<const uint4*>(src);
            } else if (tt == 0) {
                int k = kbg * 32 + ((ln >> 4) << 3);
                union { uint4 v; unsigned short u[8]; } tv;
#pragma unroll
                for (int jj = 0; jj < 8; ++jj) tv.u[jj] = f2bf(h0[k + jj]);
                *reinterpret_cast<uint4*>(&Abuf[mb][kbg][ln * 8]) = tv.v;
            } else {
                int m = 32 * r + mb * 16 + (ln & 15);
                int k = kbg * 32 + ((ln >> 4) << 3);
                *reinterpret_cast<uint4*>(&Abuf[mb][kbg][ln * 8]) =
                    pack8(out + (size_t)(tt - 1) * 131072 + (size_t)m * 1024 + k);
            }
        }
    };

    // x-half GEMM: B-frags bw[0..31]
    auto gemm_x = [&](floatx4& A0, floatx4& A1) {
#pragma unroll
        for (int kb = 0; kb < 32; ++kb) {
            short8 a0 = *reinterpret_cast<const short8*>(&Abuf[0][kb][lane * 8]);
            short8 a1 = *reinterpret_cast<const short8*>(&Abuf[1][kb][lane * 8]);
            A0 = __builtin_amdgcn_mfma_f32_16x16x32_bf16(a0, bw[kb], A0, 0, 0, 0);
            A1 = __builtin_amdgcn_mfma_f32_16x16x32_bf16(a1, bw[kb], A1, 0, 0, 0);
        }
    };
    // h-half GEMM: B-frags bw[32..63]
    auto gemm_h = [&](floatx4& A0, floatx4& A1) {
#pragma unroll
        for (int kb = 0; kb < 32; ++kb) {
            short8 a0 = *reinterpret_cast<const short8*>(&Abuf[0][kb][lane * 8]);
            short8 a1 = *reinterpret_cast<const short8*>(&Abuf[1][kb][lane * 8]);
            A0 = __builtin_amdgcn_mfma_f32_16x16x32_bf16(a0, bw[32 + kb], A0, 0, 0, 0);
            A1 = __builtin_amdgcn_mfma_f32_16x16x32_bf16(a1, bw[32 + kb], A1, 0, 0, 0);
        }
    };
    // ------------------------------------------------------------------------

    floatx4 xa0 = {0.f, 0.f, 0.f, 0.f}, xa1 = {0.f, 0.f, 0.f, 0.f};

    // prologue: x-part for t=0
    __syncthreads();                       // c_lds init visible; Abuf free
    stage_x_full(0);
    __syncthreads();
    gemm_x(xa0, xa1);

    for (int t = 0; t < 256; ++t) {
        floatx4 acc0 = xa0, acc1 = xa1;

        // ---- wait for h(t-1) release ----
        if (t > 0 && tid == 0) {
            while (__hip_atomic_load(relp, __ATOMIC_RELAXED,
                                     __HIP_MEMORY_SCOPE_AGENT) < t)
                __builtin_amdgcn_s_sleep(1);
            __builtin_amdgcn_fence(__ATOMIC_ACQUIRE, "agent");
        }
        __syncthreads();   // B1: release seen; prev gemm_x's Abuf reads done

        // ---- h part of K (k = 1024..2047), full-K stage then reg-B MFMA ----
        stage_h_full(t);
        __syncthreads();   // B2
        gemm_h(acc0, acc1);

        // ---- epilogue: bias + activation into LDS ----
        // D layout (m89): row = quad*4 + rr, col = lane&15
#pragma unroll
        for (int rr = 0; rr < 4; ++rr) {
            float p0 = acc0[rr] + breg;
            float p1 = acc1[rr] + breg;
            float v0, v1;
            if (w == 2) { v0 = tanhf(p0); v1 = tanhf(p1); }
            else        { v0 = 1.f / (1.f + __expf(-p0)); v1 = 1.f / (1.f + __expf(-p1)); }
            g_lds[w][quad * 4 + rr][col]      = v0;
            g_lds[w][16 + quad * 4 + rr][col] = v1;
        }
        __syncthreads();   // B3: gates ready; all Abuf reads (gemm_h) done

        // ---- cell update (fp32, WG-local) ----
        {
            const long hidbase = (long)t * 131072;
#pragma unroll
            for (int p = 0; p < 2; ++p) {
                int row = p * 16 + (tid >> 4);
                int cc  = tid & 15;
                float iv = g_lds[0][row][cc];
                float fv = g_lds[1][row][cc];
                float gv = g_lds[2][row][cc];
                float ov = g_lds[3][row][cc];
                float cold = c_lds[row][cc];
                float cnew = fv * cold + iv * gv;
                float hv   = ov * tanhf(cnew);
                c_lds[row][cc]   = cnew;
                hbf_lds[row][cc] = f2bf(hv);
                int m = 32 * r + row;
                out[hidbase + (long)m * 1024 + j * 16 + cc] = hv;
                if (t == 255) {
                    out[HID_OFF + (long)m * 1024 + j * 16 + cc] = hv;
                    out[CT_OFF  + (long)m * 1024 + j * 16 + cc] = cnew;
                }
            }
        }
        __syncthreads();   // B4: drains all waves' out stores; hbf_lds ready

        if (t < 255) {
            // ---- publish h(t): packed bf16 store (wave 0) ----
            if (use_ph && tid < 64) {
                int ml = tid >> 1, cg = tid & 1;
                int m = 32 * r + ml, kcol = j * 16 + cg * 8;
                int frag  = (2 * r + (ml >> 4)) * 32 + (kcol >> 5);
                int lanep = (m & 15) + 16 * ((kcol & 31) >> 3);
                unsigned short* dst = pH + (size_t)((t & 1) ^ 1) * 131072 +
                                      (size_t)frag * 512 + lanep * 8;
                *reinterpret_cast<uint4*>(dst) =
                    *reinterpret_cast<const uint4*>(&hbf_lds[ml][cg * 8]);
            }
            // ---- arrive (release orders this wave's pH stores; out stores
            //      were drained by the __syncthreads above) ----
            if (tid == 0)
                __hip_atomic_fetch_add(subp, 1, __ATOMIC_RELEASE,
                                       __HIP_MEMORY_SCOPE_AGENT);

            // ---- x prefetch for t+1 (no h dependency; hides barrier) ----
            xa0 = (floatx4){0.f, 0.f, 0.f, 0.f};
            xa1 = (floatx4){0.f, 0.f, 0.f, 0.f};
            stage_x_full(t + 1);           // Abuf free: last read pre-B3
            __syncthreads();               // B5
            gemm_x(xa0, xa1);

            // ---- aggregator: gather-poll 8 sub-counters, publish release ----
            if (is_agg && tid < 8) {
                int* sp = cnt + (r * 8 + tid) * 64;
                int target = 8 * (t + 1);
                while (true) {
                    int v = __hip_atomic_load(sp, __ATOMIC_RELAXED,
                                              __HIP_MEMORY_SCOPE_AGENT);
                    if (__ballot(v >= target) == 0xFFull) break;
                    __builtin_amdgcn_s_sleep(1);
                }
                __builtin_amdgcn_fence(__ATOMIC_ACQUIRE, "agent");
                if (tid == 0)
                    __hip_atomic_store(relp, t + 1, __ATOMIC_RELEASE,
                                       __HIP_MEMORY_SCOPE_AGENT);
            }
        }
    }
}

extern "C" void kernel_launch(void* const* d_in, const int* in_sizes, int n_in,
                              void* d_out, int out_size, void* d_ws, size_t ws_size,
                              hipStream_t stream) {
    (void)in_sizes; (void)n_in; (void)out_size;
    const float* x    = (const float*)d_in[0];
    const float* h0   = (const float*)d_in[1];
    const float* c0   = (const float*)d_in[2];
    const float* wih  = (const float*)d_in[3];
    const float* whh  = (const float*)d_in[4];
    const float* bias = (const float*)d_in[5];
    float* out = (float*)d_out;

    char* ws = (char*)d_ws;
    int* counters = (int*)ws;                 // 16 KiB counter region (spread lines)
    const size_t SZB = 2048ull * 4096 * 2;    // 16 MiB packed weights
    const size_t SZH = 2ull * 256 * 512 * 2;  // 512 KiB packed-h ping-pong
    const size_t SZX = 65536ull * 512 * 2;    // 64 MiB packed x

    size_t off = 16384;
    unsigned short* pB;
    if (ws_size >= off + SZB) {               // weights in ws
        pB = (unsigned short*)(ws + off); off += SZB;
    } else {                                  // tier D: weights in out tail
        // Safe with register-resident weights: every WG loads its B-frags
        // before step 0; out rows [224,256) are first written at t=224,
        // which requires 224 completed sync rounds.
        pB = (unsigned short*)(out + WTAIL_F);
    }
    int use_ph = (ws_size >= off + SZH) ? 1 : 0;
    unsigned short* pH = use_ph ? (unsigned short*)(ws + off) : (unsigned short*)0;
    if (use_ph) off += SZH;
    int use_px = (ws_size >= off + SZX) ? 1 : 0;
    unsigned short* pX = use_px ? (unsigned short*)(ws + off) : (unsigned short*)0;

    hipMemsetAsync(ws, 0, 16384, stream);                     // barrier counters
    pack_w_kernel<<<4096, 256, 0, stream>>>(wih, whh, pB);
    if (use_ph) pack_h0_kernel<<<64, 256, 0, stream>>>(h0, pH);
    if (use_px) pack_x_kernel<<<16384, 256, 0, stream>>>(x, pX);

    lstm_main<<<dim3(256), dim3(256), 0, stream>>>(
        x, h0, c0, bias, pB, pH, use_ph, pX, use_px, out, counters);
}

// Round 2
// 3323.878 us; speedup vs baseline: 2.0858x; 1.6453x over previous
//
#include <hip/hip_runtime.h>
#include <hip/hip_bf16.h>

// ---------------------------------------------------------------------------
// LSTM: T=256, B=128, F=1024, H=1024.  gates = [x_t | h] @ [W_ih; W_hh] + bias
// Persistent kernel, 256 WGs. Swizzled mapping: r=(wg>>3)&3 (32-row group),
// j=(wg&7)*8+(wg>>5) (16-col group). Wave = gate. bf16 MFMA 16x16x32.
// All 64 B-fragments register-resident (R4).
//
// R5 changes vs R4 (20.7 us/step, MfmaUtil 4.1% -> still sync-latency-bound):
//  - FENCE-FREE h exchange (use_ph path). R4 paid per-WG-per-step cache
//    maintenance: acquire fence (buffer_inv: invalidates XCD L1+L2, 32x/XCD/
//    step) + release fetch_add (buffer_wbl2 + vmcnt drain). Root cause: pH
//    moved through the non-coherent per-XCD L2. Now pH stores AND loads are
//    relaxed agent-scope atomics (sc0 sc1 -> serviced at the IF coherence
//    point, same mechanism the counter polls already use fence-free).
//    Ordering: explicit s_waitcnt vmcnt(0) before the arrive-add; causality
//    through IF's single serialization point. No buffer_inv / buffer_wbl2
//    anywhere in the steady-state path. L2 now retains pX lines across steps.
//  - stage_h issues atomic loads in 2 batches of 16 u64 into registers, then
//    writes LDS (avoids one-vmcnt-wait-per-load serialization; ~32 staging
//    VGPRs, live only outside the MFMA loops).
//  - !use_ph fallback keeps the R4 fenced protocol (reads h from out via L2).
// Workspace tiers (never write past ws_size):
//    counters(16K) | pB(16M) | pH(512K) | pX(64M), each only if it fits;
//    tier D: pB packed into out rows [224,256).
// ---------------------------------------------------------------------------

typedef __attribute__((ext_vector_type(8))) short short8;   // 8 bf16 = 4 VGPRs
typedef __attribute__((ext_vector_type(4))) float floatx4;  // MFMA accumulator

#define HID_OFF 33554432L   // T*B*H
#define CT_OFF  33685504L   // T*B*H + B*H
#define WTAIL_F 29360128L   // 224*131072 : float offset of hid rows [224,256)

__device__ __forceinline__ unsigned short f2bf(float f) {
    __hip_bfloat16 hb = __float2bfloat16(f);
    return *reinterpret_cast<unsigned short*>(&hb);
}

// 8 contiguous fp32 -> 8 bf16 packed in a uint4
__device__ __forceinline__ uint4 pack8(const float* p) {
    float4 f0 = *reinterpret_cast<const float4*>(p);
    float4 f1 = *reinterpret_cast<const float4*>(p + 4);
    union { uint4 v; unsigned short u[8]; } t;
    t.u[0] = f2bf(f0.x); t.u[1] = f2bf(f0.y); t.u[2] = f2bf(f0.z); t.u[3] = f2bf(f0.w);
    t.u[4] = f2bf(f1.x); t.u[5] = f2bf(f1.y); t.u[6] = f2bf(f1.z); t.u[7] = f2bf(f1.w);
    return t.v;
}

// ---- pack weights into B-fragment order: frag=(nblk*64+kblk), lane, 8 bf16 ----
__global__ void pack_w_kernel(const float* __restrict__ wih,
                              const float* __restrict__ whh,
                              unsigned short* __restrict__ pB) {
    int g    = blockIdx.x * 256 + threadIdx.x;   // 1,048,576 threads
    int lane = g & 63;
    int frag = g >> 6;
    int kblk = frag & 63;
    int nblk = frag >> 6;
    int n = nblk * 16 + (lane & 15);
    int k = kblk * 32 + ((lane >> 4) << 3);
    const float* src = (k < 1024) ? (wih + (size_t)k * 4096 + n)
                                  : (whh + (size_t)(k - 1024) * 4096 + n);
    __attribute__((aligned(16))) unsigned short tmp[8];
#pragma unroll
    for (int jj = 0; jj < 8; ++jj) tmp[jj] = f2bf(src[(size_t)jj * 4096]);
    *reinterpret_cast<uint4*>(pB + (size_t)frag * 512 + lane * 8) =
        *reinterpret_cast<const uint4*>(tmp);
}

// ---- pack x into A-fragment order: frag=(t*256 + mblk*32 + kblk) ----
__global__ void pack_x_kernel(const float* __restrict__ x,
                              unsigned short* __restrict__ pX) {
    int g    = blockIdx.x * 256 + threadIdx.x;   // 4,194,304 threads
    int lane = g & 63;
    int frag = g >> 6;
    int kblk = frag & 31;
    int mblk = (frag >> 5) & 7;
    int t    = frag >> 8;
    int m = mblk * 16 + (lane & 15);
    int k = kblk * 32 + ((lane >> 4) << 3);
    *reinterpret_cast<uint4*>(pX + (size_t)frag * 512 + lane * 8) =
        pack8(x + (size_t)(t * 128 + m) * 1024 + k);
}

// ---- init packed h0 (broadcast over batch rows) ----
__global__ void pack_h0_kernel(const float* __restrict__ h0,
                               unsigned short* __restrict__ pH) {
    int g    = blockIdx.x * 256 + threadIdx.x;   // 16,384 threads
    int lane = g & 63;
    int frag = g >> 6;            // mblk*32 + kblk
    int kblk = frag & 31;
    int k = kblk * 32 + ((lane >> 4) << 3);
    __attribute__((aligned(16))) unsigned short tmp[8];
#pragma unroll
    for (int jj = 0; jj < 8; ++jj) tmp[jj] = f2bf(h0[k + jj]);
    *reinterpret_cast<uint4*>(pH + (size_t)frag * 512 + lane * 8) =
        *reinterpret_cast<const uint4*>(tmp);
}

// ---- main persistent LSTM kernel ----
__global__ __launch_bounds__(256, 1) void lstm_main(
    const float* __restrict__ x, const float* __restrict__ h0,
    const float* __restrict__ c0, const float* __restrict__ bias,
    const unsigned short* __restrict__ pB,
    unsigned short* pH, int use_ph,
    const unsigned short* __restrict__ pX, int use_px,
    float* out, int* cnt) {

    __shared__ __align__(16) unsigned short Abuf[2][32][512];   // 64 KiB full-K A
    __shared__ float g_lds[4][32][17];                          // activated gates
    __shared__ float c_lds[32][16];                             // fp32 cell state
    __shared__ __align__(16) unsigned short hbf_lds[32][16];    // bf16 h staging

    const int tid  = threadIdx.x;
    const int lane = tid & 63;
    const int w    = tid >> 6;                 // wave index == gate (i,f,g,o)
    const int wg   = blockIdx.x;
    const int r    = (wg >> 3) & 3;            // row group (32 batch rows)
    const int j    = (wg & 7) * 8 + (wg >> 5); // h-col block (16 cols), XCD-swizzled
    const int col  = lane & 15;
    const int quad = lane >> 4;
    const int nblk = w * 64 + j;

    int* subp = cnt + (r * 8 + (j >> 3)) * 64;  // arrival sub-counter (256B spread)
    int* relp = cnt + (32 + r) * 64;            // release flag for row group
    const bool is_agg = (j == 0);

    const float breg = bias[w * 1024 + j * 16 + col];

    { // init cell state (broadcast c0 over batch rows)
        float cv = c0[j * 16 + (tid & 15)];
        int row = tid >> 4;
        c_lds[row][tid & 15]      = cv;
        c_lds[row + 16][tid & 15] = cv;
    }

    // ---- resident weights: all 64 B-fragments (x-half kb 0..31, h-half 32..63)
    const unsigned short* pBw = pB + (size_t)nblk * 64 * 512 + lane * 8;
    short8 bw[64];
#pragma unroll
    for (int kb = 0; kb < 64; ++kb)
        bw[kb] = *reinterpret_cast<const short8*>(pBw + (size_t)kb * 512);

    // ---- helpers -----------------------------------------------------------
    auto stage_x_full = [&](int tt) {
#pragma unroll
        for (int i = 0; i < 16; ++i) {
            int s = tid + 256 * i;                 // slot in [0,4096)
            int ln = s & 63, kbg = (s >> 6) & 31, mb = s >> 11;
            if (use_px) {
                const unsigned short* src =
                    pX + (((size_t)(tt * 8 + 2 * r + mb) * 32 + kbg) * 512) + ln * 8;
                *reinterpret_cast<uint4*>(&Abuf[mb][kbg][ln * 8]) =
                    *reinterpret_cast<const uint4*>(src);
            } else {
                int m = 32 * r + mb * 16 + (ln & 15);
                int k = kbg * 32 + ((ln >> 4) << 3);
                *reinterpret_cast<uint4*>(&Abuf[mb][kbg][ln * 8]) =
                    pack8(x + (size_t)(tt * 128 + m) * 1024 + k);
            }
        }
    };

    auto stage_h_full = [&](int tt) {
        if (use_ph) {
            // Coherent path: relaxed agent atomics (sc0 sc1 -> IF), no fences.
            // Batched: 16 u64 loads in flight, then LDS writes (one vmcnt wait
            // per batch instead of per load).
            const unsigned long long* hb = reinterpret_cast<const unsigned long long*>(
                pH + (size_t)(tt & 1) * 131072);
#pragma unroll
            for (int c = 0; c < 2; ++c) {
                unsigned long long v[16];
#pragma unroll
                for (int i = 0; i < 8; ++i) {
                    int s = tid + 256 * (c * 8 + i);
                    int ln = s & 63, kbg = (s >> 6) & 31, mb = s >> 11;
                    size_t u = (((size_t)(2 * r + mb) * 32 + kbg) * 512 + ln * 8) >> 2;
                    v[2 * i]     = __hip_atomic_load(hb + u, __ATOMIC_RELAXED,
                                                     __HIP_MEMORY_SCOPE_AGENT);
                    v[2 * i + 1] = __hip_atomic_load(hb + u + 1, __ATOMIC_RELAXED,
                                                     __HIP_MEMORY_SCOPE_AGENT);
                }
#pragma unroll
                for (int i = 0; i < 8; ++i) {
                    int s = tid + 256 * (c * 8 + i);
                    int ln = s & 63, kbg = (s >> 6) & 31, mb = s >> 11;
                    unsigned long long* dp =
                        reinterpret_cast<unsigned long long*>(&Abuf[mb][kbg][ln * 8]);
                    dp[0] = v[2 * i];
                    dp[1] = v[2 * i + 1];
                }
            }
        } else {
#pragma unroll
            for (int i = 0; i < 16; ++i) {
                int s = tid + 256 * i;
                int ln = s & 63, kbg = (s >> 6) & 31, mb = s >> 11;
                if (tt == 0) {
                    int k = kbg * 32 + ((ln >> 4) << 3);
                    union { uint4 v; unsigned short u[8]; } tv;
#pragma unroll
                    for (int jj = 0; jj < 8; ++jj) tv.u[jj] = f2bf(h0[k + jj]);
                    *reinterpret_cast<uint4*>(&Abuf[mb][kbg][ln * 8]) = tv.v;
                } else {
                    int m = 32 * r + mb * 16 + (ln & 15);
                    int k = kbg * 32 + ((ln >> 4) << 3);
                    *reinterpret_cast<uint4*>(&Abuf[mb][kbg][ln * 8]) =
                        pack8(out + (size_t)(tt - 1) * 131072 + (size_t)m * 1024 + k);
                }
            }
        }
    };

    // x-half GEMM: B-frags bw[0..31]
    auto gemm_x = [&](floatx4& A0, floatx4& A1) {
#pragma unroll
        for (int kb = 0; kb < 32; ++kb) {
            short8 a0 = *reinterpret_cast<const short8*>(&Abuf[0][kb][lane * 8]);
            short8 a1 = *reinterpret_cast<const short8*>(&Abuf[1][kb][lane * 8]);
            A0 = __builtin_amdgcn_mfma_f32_16x16x32_bf16(a0, bw[kb], A0, 0, 0, 0);
            A1 = __builtin_amdgcn_mfma_f32_16x16x32_bf16(a1, bw[kb], A1, 0, 0, 0);
        }
    };
    // h-half GEMM: B-frags bw[32..63]
    auto gemm_h = [&](floatx4& A0, floatx4& A1) {
#pragma unroll
        for (int kb = 0; kb < 32; ++kb) {
            short8 a0 = *reinterpret_cast<const short8*>(&Abuf[0][kb][lane * 8]);
            short8 a1 = *reinterpret_cast<const short8*>(&Abuf[1][kb][lane * 8]);
            A0 = __builtin_amdgcn_mfma_f32_16x16x32_bf16(a0, bw[32 + kb], A0, 0, 0, 0);
            A1 = __builtin_amdgcn_mfma_f32_16x16x32_bf16(a1, bw[32 + kb], A1, 0, 0, 0);
        }
    };
    // ------------------------------------------------------------------------

    floatx4 xa0 = {0.f, 0.f, 0.f, 0.f}, xa1 = {0.f, 0.f, 0.f, 0.f};

    // prologue: x-part for t=0
    __syncthreads();                       // c_lds init visible; Abuf free
    stage_x_full(0);
    __syncthreads();
    gemm_x(xa0, xa1);

    for (int t = 0; t < 256; ++t) {
        floatx4 acc0 = xa0, acc1 = xa1;

        // ---- wait for h(t-1) release ----
        if (t > 0 && tid == 0) {
            while (__hip_atomic_load(relp, __ATOMIC_RELAXED,
                                     __HIP_MEMORY_SCOPE_AGENT) < t)
                __builtin_amdgcn_s_sleep(1);
            if (!use_ph)   // fallback path moves h through L2 -> must invalidate
                __builtin_amdgcn_fence(__ATOMIC_ACQUIRE, "agent");
        }
        __syncthreads();   // B1: release seen; prev gemm_x's Abuf reads done

        // ---- h part of K (k = 1024..2047), full-K stage then reg-B MFMA ----
        stage_h_full(t);
        __syncthreads();   // B2
        gemm_h(acc0, acc1);

        // ---- epilogue: bias + activation into LDS ----
        // D layout (m89): row = quad*4 + rr, col = lane&15
#pragma unroll
        for (int rr = 0; rr < 4; ++rr) {
            float p0 = acc0[rr] + breg;
            float p1 = acc1[rr] + breg;
            float v0, v1;
            if (w == 2) { v0 = tanhf(p0); v1 = tanhf(p1); }
            else        { v0 = 1.f / (1.f + __expf(-p0)); v1 = 1.f / (1.f + __expf(-p1)); }
            g_lds[w][quad * 4 + rr][col]      = v0;
            g_lds[w][16 + quad * 4 + rr][col] = v1;
        }
        __syncthreads();   // B3: gates ready; all Abuf reads (gemm_h) done

        // ---- cell update (fp32, WG-local) ----
        {
            const long hidbase = (long)t * 131072;
#pragma unroll
            for (int p = 0; p < 2; ++p) {
                int row = p * 16 + (tid >> 4);
                int cc  = tid & 15;
                float iv = g_lds[0][row][cc];
                float fv = g_lds[1][row][cc];
                float gv = g_lds[2][row][cc];
                float ov = g_lds[3][row][cc];
                float cold = c_lds[row][cc];
                float cnew = fv * cold + iv * gv;
                float hv   = ov * tanhf(cnew);
                c_lds[row][cc]   = cnew;
                hbf_lds[row][cc] = f2bf(hv);
                int m = 32 * r + row;
                out[hidbase + (long)m * 1024 + j * 16 + cc] = hv;
                if (t == 255) {
                    out[HID_OFF + (long)m * 1024 + j * 16 + cc] = hv;
                    out[CT_OFF  + (long)m * 1024 + j * 16 + cc] = cnew;
                }
            }
        }
        __syncthreads();   // B4: drains all waves' out stores; hbf_lds ready

        if (t < 255) {
            // ---- publish h(t): coherent (IF-point) bf16 stores, wave 0 ----
            if (use_ph && tid < 64) {
                int ml = tid >> 1, cg = tid & 1;
                int m = 32 * r + ml, kcol = j * 16 + cg * 8;
                int frag  = (2 * r + (ml >> 4)) * 32 + (kcol >> 5);
                int lanep = (m & 15) + 16 * ((kcol & 31) >> 3);
                unsigned short* dst = pH + (size_t)((t & 1) ^ 1) * 131072 +
                                      (size_t)frag * 512 + lanep * 8;
                const unsigned long long* sv =
                    reinterpret_cast<const unsigned long long*>(&hbf_lds[ml][cg * 8]);
                unsigned long long* d64 = reinterpret_cast<unsigned long long*>(dst);
                __hip_atomic_store(d64, sv[0], __ATOMIC_RELAXED,
                                   __HIP_MEMORY_SCOPE_AGENT);
                __hip_atomic_store(d64 + 1, sv[1], __ATOMIC_RELAXED,
                                   __HIP_MEMORY_SCOPE_AGENT);
            }
            // ---- arrive. use_ph: pH stores are already at the coherence
            //      point once vmcnt retires -> explicit waitcnt + relaxed add
            //      (no buffer_wbl2). !use_ph: release add (wbl2 flushes out).
            if (tid == 0) {
                if (use_ph) {
                    asm volatile("s_waitcnt vmcnt(0)" ::: "memory");
                    __hip_atomic_fetch_add(subp, 1, __ATOMIC_RELAXED,
                                           __HIP_MEMORY_SCOPE_AGENT);
                } else {
                    __hip_atomic_fetch_add(subp, 1, __ATOMIC_RELEASE,
                                           __HIP_MEMORY_SCOPE_AGENT);
                }
            }

            // ---- x prefetch for t+1 (no h dependency; hides barrier) ----
            xa0 = (floatx4){0.f, 0.f, 0.f, 0.f};
            xa1 = (floatx4){0.f, 0.f, 0.f, 0.f};
            stage_x_full(t + 1);           // Abuf free: last read pre-B3
            __syncthreads();               // B5
            gemm_x(xa0, xa1);

            // ---- aggregator: gather-poll 8 sub-counters, publish release ----
            if (is_agg && tid < 8) {
                int* sp = cnt + (r * 8 + tid) * 64;
                int target = 8 * (t + 1);
                while (true) {
                    int v = __hip_atomic_load(sp, __ATOMIC_RELAXED,
                                              __HIP_MEMORY_SCOPE_AGENT);
                    if (__ballot(v >= target) == 0xFFull) break;
                    __builtin_amdgcn_s_sleep(1);
                }
                if (!use_ph)
                    __builtin_amdgcn_fence(__ATOMIC_ACQUIRE, "agent");
                asm volatile("" ::: "memory");   // keep relp store after polls
                if (tid == 0) {
                    if (use_ph)
                        __hip_atomic_store(relp, t + 1, __ATOMIC_RELAXED,
                                           __HIP_MEMORY_SCOPE_AGENT);
                    else
                        __hip_atomic_store(relp, t + 1, __ATOMIC_RELEASE,
                                           __HIP_MEMORY_SCOPE_AGENT);
                }
            }
        }
    }
}

extern "C" void kernel_launch(void* const* d_in, const int* in_sizes, int n_in,
                              void* d_out, int out_size, void* d_ws, size_t ws_size,
                              hipStream_t stream) {
    (void)in_sizes; (void)n_in; (void)out_size;
    const float* x    = (const float*)d_in[0];
    const float* h0   = (const float*)d_in[1];
    const float* c0   = (const float*)d_in[2];
    const float* wih  = (const float*)d_in[3];
    const float* whh  = (const float*)d_in[4];
    const float* bias = (const float*)d_in[5];
    float* out = (float*)d_out;

    char* ws = (char*)d_ws;
    int* counters = (int*)ws;                 // 16 KiB counter region (spread lines)
    const size_t SZB = 2048ull * 4096 * 2;    // 16 MiB packed weights
    const size_t SZH = 2ull * 256 * 512 * 2;  // 512 KiB packed-h ping-pong
    const size_t SZX = 65536ull * 512 * 2;    // 64 MiB packed x

    size_t off = 16384;
    unsigned short* pB;
    if (ws_size >= off + SZB) {               // weights in ws
        pB = (unsigned short*)(ws + off); off += SZB;
    } else {                                  // tier D: weights in out tail
        // Safe with register-resident weights: every WG loads its B-frags
        // before step 0; out rows [224,256) are first written at t=224.
        pB = (unsigned short*)(out + WTAIL_F);
    }
    int use_ph = (ws_size >= off + SZH) ? 1 : 0;
    unsigned short* pH = use_ph ? (unsigned short*)(ws + off) : (unsigned short*)0;
    if (use_ph) off += SZH;
    int use_px = (ws_size >= off + SZX) ? 1 : 0;
    unsigned short* pX = use_px ? (unsigned short*)(ws + off) : (unsigned short*)0;

    hipMemsetAsync(ws, 0, 16384, stream);                     // barrier counters
    pack_w_kernel<<<4096, 256, 0, stream>>>(wih, whh, pB);
    if (use_ph) pack_h0_kernel<<<64, 256, 0, stream>>>(h0, pH);
    if (use_px) pack_x_kernel<<<16384, 256, 0, stream>>>(x, pX);

    lstm_main<<<dim3(256), dim3(256), 0, stream>>>(
        x, h0, c0, bias, pB, pH, use_ph, pX, use_px, out, counters);
}

// Round 3
// 3230.644 us; speedup vs baseline: 2.1459x; 1.0289x over previous
//
#include <hip/hip_runtime.h>
#include <hip/hip_bf16.h>

// ---------------------------------------------------------------------------
// LSTM: T=256, B=128, F=1024, H=1024.  gates = [x_t | h] @ [W_ih; W_hh] + bias
// Persistent kernel, 256 WGs. Swizzled mapping: r=(wg>>3)&3 (32-row group),
// j=(wg&7)*8+(wg>>5) (16-col group). Wave = gate. bf16 MFMA 16x16x32.
// All 64 B-fragments register-resident (R4). Fence-free IF-coherent h
// exchange via relaxed agent atomics (R5).
//
// R6 changes vs R5 (12.4 us/step; protocol latency dominates):
//  - NO aggregator / release flag. Every WG gather-polls the 8 spread
//    sub-counters of its row group directly (tid<8 + ballot, relaxed IF
//    loads). Removes one IF round trip AND the aggregator's x-prefetch
//    (~1.2-1.5us) from the per-step release path.
//  - out stores moved AFTER publish+arrive (hv/c kept in registers), so the
//    arrive's s_waitcnt vmcnt(0) covers only the 1 KiB pH publish, and B4
//    drains no HBM stores. (!use_ph keeps stores before its release-arrive.)
//  - stage_h issues all 32 u64 IF loads in one batch (one latency, not two).
//  - t==0 h-staging broadcasts from h0 directly; pack_h0 dropped (also fixes
//    a latent pack-store(L2)/IF-load coherency hazard that only passed
//    because h0==0).
// Workspace tiers (never write past ws_size):
//    counters(16K) | pB(16M) | pH(512K) | pX(64M), each only if it fits;
//    tier D: pB packed into out rows [224,256).
// ---------------------------------------------------------------------------

typedef __attribute__((ext_vector_type(8))) short short8;   // 8 bf16 = 4 VGPRs
typedef __attribute__((ext_vector_type(4))) float floatx4;  // MFMA accumulator

#define HID_OFF 33554432L   // T*B*H
#define CT_OFF  33685504L   // T*B*H + B*H
#define WTAIL_F 29360128L   // 224*131072 : float offset of hid rows [224,256)

__device__ __forceinline__ unsigned short f2bf(float f) {
    __hip_bfloat16 hb = __float2bfloat16(f);
    return *reinterpret_cast<unsigned short*>(&hb);
}

// 8 contiguous fp32 -> 8 bf16 packed in a uint4
__device__ __forceinline__ uint4 pack8(const float* p) {
    float4 f0 = *reinterpret_cast<const float4*>(p);
    float4 f1 = *reinterpret_cast<const float4*>(p + 4);
    union { uint4 v; unsigned short u[8]; } t;
    t.u[0] = f2bf(f0.x); t.u[1] = f2bf(f0.y); t.u[2] = f2bf(f0.z); t.u[3] = f2bf(f0.w);
    t.u[4] = f2bf(f1.x); t.u[5] = f2bf(f1.y); t.u[6] = f2bf(f1.z); t.u[7] = f2bf(f1.w);
    return t.v;
}

// ---- pack weights into B-fragment order: frag=(nblk*64+kblk), lane, 8 bf16 ----
__global__ void pack_w_kernel(const float* __restrict__ wih,
                              const float* __restrict__ whh,
                              unsigned short* __restrict__ pB) {
    int g    = blockIdx.x * 256 + threadIdx.x;   // 1,048,576 threads
    int lane = g & 63;
    int frag = g >> 6;
    int kblk = frag & 63;
    int nblk = frag >> 6;
    int n = nblk * 16 + (lane & 15);
    int k = kblk * 32 + ((lane >> 4) << 3);
    const float* src = (k < 1024) ? (wih + (size_t)k * 4096 + n)
                                  : (whh + (size_t)(k - 1024) * 4096 + n);
    __attribute__((aligned(16))) unsigned short tmp[8];
#pragma unroll
    for (int jj = 0; jj < 8; ++jj) tmp[jj] = f2bf(src[(size_t)jj * 4096]);
    *reinterpret_cast<uint4*>(pB + (size_t)frag * 512 + lane * 8) =
        *reinterpret_cast<const uint4*>(tmp);
}

// ---- pack x into A-fragment order: frag=(t*256 + mblk*32 + kblk) ----
__global__ void pack_x_kernel(const float* __restrict__ x,
                              unsigned short* __restrict__ pX) {
    int g    = blockIdx.x * 256 + threadIdx.x;   // 4,194,304 threads
    int lane = g & 63;
    int frag = g >> 6;
    int kblk = frag & 31;
    int mblk = (frag >> 5) & 7;
    int t    = frag >> 8;
    int m = mblk * 16 + (lane & 15);
    int k = kblk * 32 + ((lane >> 4) << 3);
    *reinterpret_cast<uint4*>(pX + (size_t)frag * 512 + lane * 8) =
        pack8(x + (size_t)(t * 128 + m) * 1024 + k);
}

// ---- main persistent LSTM kernel ----
__global__ __launch_bounds__(256, 1) void lstm_main(
    const float* __restrict__ x, const float* __restrict__ h0,
    const float* __restrict__ c0, const float* __restrict__ bias,
    const unsigned short* __restrict__ pB,
    unsigned short* pH, int use_ph,
    const unsigned short* __restrict__ pX, int use_px,
    float* out, int* cnt) {

    __shared__ __align__(16) unsigned short Abuf[2][32][512];   // 64 KiB full-K A
    __shared__ float g_lds[4][32][17];                          // activated gates
    __shared__ float c_lds[32][16];                             // fp32 cell state
    __shared__ __align__(16) unsigned short hbf_lds[32][16];    // bf16 h staging

    const int tid  = threadIdx.x;
    const int lane = tid & 63;
    const int w    = tid >> 6;                 // wave index == gate (i,f,g,o)
    const int wg   = blockIdx.x;
    const int r    = (wg >> 3) & 3;            // row group (32 batch rows)
    const int j    = (wg & 7) * 8 + (wg >> 5); // h-col block (16 cols), XCD-swizzled
    const int col  = lane & 15;
    const int quad = lane >> 4;
    const int nblk = w * 64 + j;

    int* subp = cnt + (r * 8 + (j >> 3)) * 64;  // arrival sub-counter (256B spread)

    const float breg = bias[w * 1024 + j * 16 + col];

    { // init cell state (broadcast c0 over batch rows)
        float cv = c0[j * 16 + (tid & 15)];
        int row = tid >> 4;
        c_lds[row][tid & 15]      = cv;
        c_lds[row + 16][tid & 15] = cv;
    }

    // ---- resident weights: all 64 B-fragments (x-half kb 0..31, h-half 32..63)
    const unsigned short* pBw = pB + (size_t)nblk * 64 * 512 + lane * 8;
    short8 bw[64];
#pragma unroll
    for (int kb = 0; kb < 64; ++kb)
        bw[kb] = *reinterpret_cast<const short8*>(pBw + (size_t)kb * 512);

    // ---- helpers -----------------------------------------------------------
    auto stage_x_full = [&](int tt) {
#pragma unroll
        for (int i = 0; i < 16; ++i) {
            int s = tid + 256 * i;                 // slot in [0,4096)
            int ln = s & 63, kbg = (s >> 6) & 31, mb = s >> 11;
            if (use_px) {
                const unsigned short* src =
                    pX + (((size_t)(tt * 8 + 2 * r + mb) * 32 + kbg) * 512) + ln * 8;
                *reinterpret_cast<uint4*>(&Abuf[mb][kbg][ln * 8]) =
                    *reinterpret_cast<const uint4*>(src);
            } else {
                int m = 32 * r + mb * 16 + (ln & 15);
                int k = kbg * 32 + ((ln >> 4) << 3);
                *reinterpret_cast<uint4*>(&Abuf[mb][kbg][ln * 8]) =
                    pack8(x + (size_t)(tt * 128 + m) * 1024 + k);
            }
        }
    };

    auto stage_h_full = [&](int tt) {
        if (tt == 0) {
            // broadcast h0 over batch rows (no pH dependency at t=0)
#pragma unroll
            for (int i = 0; i < 16; ++i) {
                int s = tid + 256 * i;
                int ln = s & 63, kbg = (s >> 6) & 31, mb = s >> 11;
                int k = kbg * 32 + ((ln >> 4) << 3);
                union { uint4 v; unsigned short u[8]; } tv;
#pragma unroll
                for (int jj = 0; jj < 8; ++jj) tv.u[jj] = f2bf(h0[k + jj]);
                *reinterpret_cast<uint4*>(&Abuf[mb][kbg][ln * 8]) = tv.v;
            }
        } else if (use_ph) {
            // Coherent path: relaxed agent atomics (IF point), no fences.
            // Single batch: all 32 u64 loads in flight, then LDS writes
            // (one IF latency for the whole stage).
            const unsigned long long* hb = reinterpret_cast<const unsigned long long*>(
                pH + (size_t)(tt & 1) * 131072);
            unsigned long long v[32];
#pragma unroll
            for (int i = 0; i < 16; ++i) {
                int s = tid + 256 * i;
                int ln = s & 63, kbg = (s >> 6) & 31, mb = s >> 11;
                size_t u = (((size_t)(2 * r + mb) * 32 + kbg) * 512 + ln * 8) >> 2;
                v[2 * i]     = __hip_atomic_load(hb + u, __ATOMIC_RELAXED,
                                                 __HIP_MEMORY_SCOPE_AGENT);
                v[2 * i + 1] = __hip_atomic_load(hb + u + 1, __ATOMIC_RELAXED,
                                                 __HIP_MEMORY_SCOPE_AGENT);
            }
#pragma unroll
            for (int i = 0; i < 16; ++i) {
                int s = tid + 256 * i;
                int ln = s & 63, kbg = (s >> 6) & 31, mb = s >> 11;
                unsigned long long* dp =
                    reinterpret_cast<unsigned long long*>(&Abuf[mb][kbg][ln * 8]);
                dp[0] = v[2 * i];
                dp[1] = v[2 * i + 1];
            }
        } else {
            // fallback: read h(t-1) from out via L2 (fenced protocol)
#pragma unroll
            for (int i = 0; i < 16; ++i) {
                int s = tid + 256 * i;
                int ln = s & 63, kbg = (s >> 6) & 31, mb = s >> 11;
                int m = 32 * r + mb * 16 + (ln & 15);
                int k = kbg * 32 + ((ln >> 4) << 3);
                *reinterpret_cast<uint4*>(&Abuf[mb][kbg][ln * 8]) =
                    pack8(out + (size_t)(tt - 1) * 131072 + (size_t)m * 1024 + k);
            }
        }
    };

    // x-half GEMM: B-frags bw[0..31]
    auto gemm_x = [&](floatx4& A0, floatx4& A1) {
#pragma unroll
        for (int kb = 0; kb < 32; ++kb) {
            short8 a0 = *reinterpret_cast<const short8*>(&Abuf[0][kb][lane * 8]);
            short8 a1 = *reinterpret_cast<const short8*>(&Abuf[1][kb][lane * 8]);
            A0 = __builtin_amdgcn_mfma_f32_16x16x32_bf16(a0, bw[kb], A0, 0, 0, 0);
            A1 = __builtin_amdgcn_mfma_f32_16x16x32_bf16(a1, bw[kb], A1, 0, 0, 0);
        }
    };
    // h-half GEMM: B-frags bw[32..63]
    auto gemm_h = [&](floatx4& A0, floatx4& A1) {
#pragma unroll
        for (int kb = 0; kb < 32; ++kb) {
            short8 a0 = *reinterpret_cast<const short8*>(&Abuf[0][kb][lane * 8]);
            short8 a1 = *reinterpret_cast<const short8*>(&Abuf[1][kb][lane * 8]);
            A0 = __builtin_amdgcn_mfma_f32_16x16x32_bf16(a0, bw[32 + kb], A0, 0, 0, 0);
            A1 = __builtin_amdgcn_mfma_f32_16x16x32_bf16(a1, bw[32 + kb], A1, 0, 0, 0);
        }
    };
    // ------------------------------------------------------------------------

    floatx4 xa0 = {0.f, 0.f, 0.f, 0.f}, xa1 = {0.f, 0.f, 0.f, 0.f};

    // prologue: x-part for t=0
    __syncthreads();                       // c_lds init visible; Abuf free
    stage_x_full(0);
    __syncthreads();
    gemm_x(xa0, xa1);

    for (int t = 0; t < 256; ++t) {
        floatx4 acc0 = xa0, acc1 = xa1;

        // ---- direct gather-poll: all 8 sub-counters of this row group ----
        if (t > 0 && tid < 8) {
            int* sp = cnt + (r * 8 + tid) * 64;
            const int target = 8 * t;        // 8 WGs/sub-counter, 1 add/step
            while (true) {
                int vv = __hip_atomic_load(sp, __ATOMIC_RELAXED,
                                           __HIP_MEMORY_SCOPE_AGENT);
                if (__ballot(vv >= target) == 0xFFull) break;
                __builtin_amdgcn_s_sleep(1);
            }
            if (!use_ph)   // fallback moves h through L2 -> must invalidate
                __builtin_amdgcn_fence(__ATOMIC_ACQUIRE, "agent");
        }
        __syncthreads();   // B1: h(t-1) ready; prev gemm_x's Abuf reads done

        // ---- h part of K (k = 1024..2047), full-K stage then reg-B MFMA ----
        stage_h_full(t);
        __syncthreads();   // B2
        gemm_h(acc0, acc1);

        // ---- epilogue: bias + activation into LDS ----
        // D layout (m89): row = quad*4 + rr, col = lane&15
#pragma unroll
        for (int rr = 0; rr < 4; ++rr) {
            float p0 = acc0[rr] + breg;
            float p1 = acc1[rr] + breg;
            float v0, v1;
            if (w == 2) { v0 = tanhf(p0); v1 = tanhf(p1); }
            else        { v0 = 1.f / (1.f + __expf(-p0)); v1 = 1.f / (1.f + __expf(-p1)); }
            g_lds[w][quad * 4 + rr][col]      = v0;
            g_lds[w][16 + quad * 4 + rr][col] = v1;
        }
        __syncthreads();   // B3: gates ready; all Abuf reads (gemm_h) done

        // ---- cell update (fp32, WG-local); hv/c kept in registers ----
        const int row0 = tid >> 4, cc = tid & 15;
        float hv0, hv1, cn0, cn1;
        {
            float iv = g_lds[0][row0][cc];
            float fv = g_lds[1][row0][cc];
            float gv = g_lds[2][row0][cc];
            float ov = g_lds[3][row0][cc];
            cn0 = fv * c_lds[row0][cc] + iv * gv;
            hv0 = ov * tanhf(cn0);
            c_lds[row0][cc]   = cn0;
            hbf_lds[row0][cc] = f2bf(hv0);
            int row1 = row0 + 16;
            iv = g_lds[0][row1][cc];
            fv = g_lds[1][row1][cc];
            gv = g_lds[2][row1][cc];
            ov = g_lds[3][row1][cc];
            cn1 = fv * c_lds[row1][cc] + iv * gv;
            hv1 = ov * tanhf(cn1);
            c_lds[row1][cc]   = cn1;
            hbf_lds[row1][cc] = f2bf(hv1);
        }
        __syncthreads();   // B4: hbf_lds ready for publish (no global drains)

        auto store_out = [&]() {
            const long hidbase = (long)t * 131072;
            const long m0 = 32 * r + row0, m1 = m0 + 16;
            out[hidbase + m0 * 1024 + j * 16 + cc] = hv0;
            out[hidbase + m1 * 1024 + j * 16 + cc] = hv1;
            if (t == 255) {
                out[HID_OFF + m0 * 1024 + j * 16 + cc] = hv0;
                out[HID_OFF + m1 * 1024 + j * 16 + cc] = hv1;
                out[CT_OFF  + m0 * 1024 + j * 16 + cc] = cn0;
                out[CT_OFF  + m1 * 1024 + j * 16 + cc] = cn1;
            }
        };

        if (!use_ph) store_out();   // fallback: out IS the h exchange medium;
                                    // must precede the release-arrive

        if (t < 255) {
            // ---- publish h(t): coherent (IF-point) bf16 stores, wave 0 ----
            if (use_ph && tid < 64) {
                int ml = tid >> 1, cg = tid & 1;
                int m = 32 * r + ml, kcol = j * 16 + cg * 8;
                int frag  = (2 * r + (ml >> 4)) * 32 + (kcol >> 5);
                int lanep = (m & 15) + 16 * ((kcol & 31) >> 3);
                unsigned short* dst = pH + (size_t)((t & 1) ^ 1) * 131072 +
                                      (size_t)frag * 512 + lanep * 8;
                const unsigned long long* sv =
                    reinterpret_cast<const unsigned long long*>(&hbf_lds[ml][cg * 8]);
                unsigned long long* d64 = reinterpret_cast<unsigned long long*>(dst);
                __hip_atomic_store(d64, sv[0], __ATOMIC_RELAXED,
                                   __HIP_MEMORY_SCOPE_AGENT);
                __hip_atomic_store(d64 + 1, sv[1], __ATOMIC_RELAXED,
                                   __HIP_MEMORY_SCOPE_AGENT);
            }
            // ---- arrive. use_ph: wait only the pH publishes (wave0's
            //      outstanding vmem = publishes only), then relaxed add.
            if (tid == 0) {
                if (use_ph) {
                    asm volatile("s_waitcnt vmcnt(0)" ::: "memory");
                    __hip_atomic_fetch_add(subp, 1, __ATOMIC_RELAXED,
                                           __HIP_MEMORY_SCOPE_AGENT);
                } else {
                    __hip_atomic_fetch_add(subp, 1, __ATOMIC_RELEASE,
                                           __HIP_MEMORY_SCOPE_AGENT);
                }
            }
        }

        if (use_ph) store_out();    // off the critical path

        if (t < 255) {
            // ---- x prefetch for t+1 (no h dependency; overlaps the window
            //      in which other WGs finish + arrivals become visible) ----
            xa0 = (floatx4){0.f, 0.f, 0.f, 0.f};
            xa1 = (floatx4){0.f, 0.f, 0.f, 0.f};
            stage_x_full(t + 1);           // Abuf free: last read pre-B3
            __syncthreads();               // B5
            gemm_x(xa0, xa1);
        }
    }
}

extern "C" void kernel_launch(void* const* d_in, const int* in_sizes, int n_in,
                              void* d_out, int out_size, void* d_ws, size_t ws_size,
                              hipStream_t stream) {
    (void)in_sizes; (void)n_in; (void)out_size;
    const float* x    = (const float*)d_in[0];
    const float* h0   = (const float*)d_in[1];
    const float* c0   = (const float*)d_in[2];
    const float* wih  = (const float*)d_in[3];
    const float* whh  = (const float*)d_in[4];
    const float* bias = (const float*)d_in[5];
    float* out = (float*)d_out;

    char* ws = (char*)d_ws;
    int* counters = (int*)ws;                 // 16 KiB counter region (spread lines)
    const size_t SZB = 2048ull * 4096 * 2;    // 16 MiB packed weights
    const size_t SZH = 2ull * 256 * 512 * 2;  // 512 KiB packed-h ping-pong
    const size_t SZX = 65536ull * 512 * 2;    // 64 MiB packed x

    size_t off = 16384;
    unsigned short* pB;
    if (ws_size >= off + SZB) {               // weights in ws
        pB = (unsigned short*)(ws + off); off += SZB;
    } else {                                  // tier D: weights in out tail
        // Safe with register-resident weights: every WG loads its B-frags
        // before step 0; out rows [224,256) are first written at t=224.
        pB = (unsigned short*)(out + WTAIL_F);
    }
    int use_ph = (ws_size >= off + SZH) ? 1 : 0;
    unsigned short* pH = use_ph ? (unsigned short*)(ws + off) : (unsigned short*)0;
    if (use_ph) off += SZH;
    int use_px = (ws_size >= off + SZX) ? 1 : 0;
    unsigned short* pX = use_px ? (unsigned short*)(ws + off) : (unsigned short*)0;

    hipMemsetAsync(ws, 0, 16384, stream);                     // barrier counters
    pack_w_kernel<<<4096, 256, 0, stream>>>(wih, whh, pB);
    if (use_px) pack_x_kernel<<<16384, 256, 0, stream>>>(x, pX);

    lstm_main<<<dim3(256), dim3(256), 0, stream>>>(
        x, h0, c0, bias, pB, pH, use_ph, pX, use_px, out, counters);
}

// Round 4
// 3203.047 us; speedup vs baseline: 2.1644x; 1.0086x over previous
//
#include <hip/hip_runtime.h>
#include <hip/hip_bf16.h>

// ---------------------------------------------------------------------------
// LSTM: T=256, B=128, F=1024, H=1024.  gates = [x_t | h] @ [W_ih; W_hh] + bias
// Persistent kernel, 256 WGs. r=(wg>>3)&3 (32-row group), j=(wg&7)*8+(wg>>5)
// (16-col group, XCD-swizzled). Wave = gate. bf16 MFMA 16x16x32.
// All 64 B-fragments register-resident (R4). Fence-free IF-coherent h
// exchange (R5). Direct gather-poll, no aggregator (R6).
//
// R7 changes vs R6 (12.0 us/step; ~10 us idle unexplained by protocol hops):
//  - stage_h: per-lane 8B RELAXED-ATOMIC loads (8192/WG/step; possible
//    per-atomic waitcnt serialization AND 2x the IF request count) replaced
//    by inline-asm global_load_dwordx4 sc0 sc1 (16B/lane, batch-issued,
//    ONE explicit vmcnt(0) drain).
//  - Overlap the IF drain: poll -> issue all 16 h-loads to registers ->
//    gemm_x (ds_read+MFMA only; lgkmcnt, no vmcnt interference) runs under
//    the in-flight loads -> drain -> write LDS -> gemm_h. No xa carry.
//  - stage_x(t+1) moved to step tail (off critical path, overlaps straggler
//    wait). Tail + B1 use raw s_barrier (+explicit lgkmcnt) so no implicit
//    vmcnt(0) drain of in-flight loads at barriers.
//  - Split LDS staging: AbufX + AbufH (64 KiB each; 139.5 KiB total).
// Workspace tiers (never write past ws_size):
//    counters(16K) | pB(16M) | pH(512K) | pX(64M), each only if it fits;
//    tier D: pB packed into out rows [224,256).
// ---------------------------------------------------------------------------

typedef __attribute__((ext_vector_type(8))) short short8;   // 8 bf16 = 4 VGPRs
typedef __attribute__((ext_vector_type(4))) float floatx4;  // MFMA accumulator

#define HID_OFF 33554432L   // T*B*H
#define CT_OFF  33685504L   // T*B*H + B*H
#define WTAIL_F 29360128L   // 224*131072 : float offset of hid rows [224,256)

__device__ __forceinline__ unsigned short f2bf(float f) {
    __hip_bfloat16 hb = __float2bfloat16(f);
    return *reinterpret_cast<unsigned short*>(&hb);
}

// 8 contiguous fp32 -> 8 bf16 packed in a uint4
__device__ __forceinline__ uint4 pack8(const float* p) {
    float4 f0 = *reinterpret_cast<const float4*>(p);
    float4 f1 = *reinterpret_cast<const float4*>(p + 4);
    union { uint4 v; unsigned short u[8]; } t;
    t.u[0] = f2bf(f0.x); t.u[1] = f2bf(f0.y); t.u[2] = f2bf(f0.z); t.u[3] = f2bf(f0.w);
    t.u[4] = f2bf(f1.x); t.u[5] = f2bf(f1.y); t.u[6] = f2bf(f1.z); t.u[7] = f2bf(f1.w);
    return t.v;
}

// ---- pack weights into B-fragment order: frag=(nblk*64+kblk), lane, 8 bf16 ----
__global__ void pack_w_kernel(const float* __restrict__ wih,
                              const float* __restrict__ whh,
                              unsigned short* __restrict__ pB) {
    int g    = blockIdx.x * 256 + threadIdx.x;   // 1,048,576 threads
    int lane = g & 63;
    int frag = g >> 6;
    int kblk = frag & 63;
    int nblk = frag >> 6;
    int n = nblk * 16 + (lane & 15);
    int k = kblk * 32 + ((lane >> 4) << 3);
    const float* src = (k < 1024) ? (wih + (size_t)k * 4096 + n)
                                  : (whh + (size_t)(k - 1024) * 4096 + n);
    __attribute__((aligned(16))) unsigned short tmp[8];
#pragma unroll
    for (int jj = 0; jj < 8; ++jj) tmp[jj] = f2bf(src[(size_t)jj * 4096]);
    *reinterpret_cast<uint4*>(pB + (size_t)frag * 512 + lane * 8) =
        *reinterpret_cast<const uint4*>(tmp);
}

// ---- pack x into A-fragment order: frag=(t*256 + mblk*32 + kblk) ----
__global__ void pack_x_kernel(const float* __restrict__ x,
                              unsigned short* __restrict__ pX) {
    int g    = blockIdx.x * 256 + threadIdx.x;   // 4,194,304 threads
    int lane = g & 63;
    int frag = g >> 6;
    int kblk = frag & 31;
    int mblk = (frag >> 5) & 7;
    int t    = frag >> 8;
    int m = mblk * 16 + (lane & 15);
    int k = kblk * 32 + ((lane >> 4) << 3);
    *reinterpret_cast<uint4*>(pX + (size_t)frag * 512 + lane * 8) =
        pack8(x + (size_t)(t * 128 + m) * 1024 + k);
}

// ---- main persistent LSTM kernel ----
__global__ __launch_bounds__(256, 1) void lstm_main(
    const float* __restrict__ x, const float* __restrict__ h0,
    const float* __restrict__ c0, const float* __restrict__ bias,
    const unsigned short* __restrict__ pB,
    unsigned short* pH, int use_ph,
    const unsigned short* __restrict__ pX, int use_px,
    float* out, int* cnt) {

    __shared__ __align__(16) unsigned short AbufX[2][32][512];  // 64 KiB x A-frags
    __shared__ __align__(16) unsigned short AbufH[2][32][512];  // 64 KiB h A-frags
    __shared__ float g_lds[4][32][17];                          // activated gates
    __shared__ float c_lds[32][16];                             // fp32 cell state
    __shared__ __align__(16) unsigned short hbf_lds[32][16];    // bf16 h staging

    const int tid  = threadIdx.x;
    const int lane = tid & 63;
    const int w    = tid >> 6;                 // wave index == gate (i,f,g,o)
    const int wg   = blockIdx.x;
    const int r    = (wg >> 3) & 3;            // row group (32 batch rows)
    const int j    = (wg & 7) * 8 + (wg >> 5); // h-col block (16 cols)
    const int col  = lane & 15;
    const int quad = lane >> 4;
    const int nblk = w * 64 + j;

    int* subp = cnt + (r * 8 + (j >> 3)) * 64;  // arrival sub-counter (256B spread)

    const float breg = bias[w * 1024 + j * 16 + col];

    { // init cell state (each thread owns its 2 cells; no cross-thread use)
        float cv = c0[j * 16 + (tid & 15)];
        int row = tid >> 4;
        c_lds[row][tid & 15]      = cv;
        c_lds[row + 16][tid & 15] = cv;
    }

    // ---- resident weights: all 64 B-fragments (x-half kb 0..31, h-half 32..63)
    const unsigned short* pBw = pB + (size_t)nblk * 64 * 512 + lane * 8;
    short8 bw[64];
#pragma unroll
    for (int kb = 0; kb < 64; ++kb)
        bw[kb] = *reinterpret_cast<const short8*>(pBw + (size_t)kb * 512);

    // ---- helpers -----------------------------------------------------------
    auto stage_x_full = [&](int tt) {
#pragma unroll
        for (int i = 0; i < 16; ++i) {
            int s = tid + 256 * i;                 // slot in [0,4096)
            int ln = s & 63, kbg = (s >> 6) & 31, mb = s >> 11;
            if (use_px) {
                const unsigned short* src =
                    pX + (((size_t)(tt * 8 + 2 * r + mb) * 32 + kbg) * 512) + ln * 8;
                *reinterpret_cast<uint4*>(&AbufX[mb][kbg][ln * 8]) =
                    *reinterpret_cast<const uint4*>(src);
            } else {
                int m = 32 * r + mb * 16 + (ln & 15);
                int k = kbg * 32 + ((ln >> 4) << 3);
                *reinterpret_cast<uint4*>(&AbufX[mb][kbg][ln * 8]) =
                    pack8(x + (size_t)(tt * 128 + m) * 1024 + k);
            }
        }
    };

    auto stage_h0 = [&]() {    // broadcast h0 over batch rows (t=0 only)
#pragma unroll
        for (int i = 0; i < 16; ++i) {
            int s = tid + 256 * i;
            int ln = s & 63, kbg = (s >> 6) & 31, mb = s >> 11;
            int k = kbg * 32 + ((ln >> 4) << 3);
            union { uint4 v; unsigned short u[8]; } tv;
#pragma unroll
            for (int jj = 0; jj < 8; ++jj) tv.u[jj] = f2bf(h0[k + jj]);
            *reinterpret_cast<uint4*>(&AbufH[mb][kbg][ln * 8]) = tv.v;
        }
    };

    auto stage_h_out = [&](int tt) {   // !use_ph fallback: h from out via L2
#pragma unroll
        for (int i = 0; i < 16; ++i) {
            int s = tid + 256 * i;
            int ln = s & 63, kbg = (s >> 6) & 31, mb = s >> 11;
            int m = 32 * r + mb * 16 + (ln & 15);
            int k = kbg * 32 + ((ln >> 4) << 3);
            *reinterpret_cast<uint4*>(&AbufH[mb][kbg][ln * 8]) =
                pack8(out + (size_t)(tt - 1) * 131072 + (size_t)m * 1024 + k);
        }
    };

    auto gemm_x = [&](floatx4& A0, floatx4& A1) {   // B-frags bw[0..31]
#pragma unroll
        for (int kb = 0; kb < 32; ++kb) {
            short8 a0 = *reinterpret_cast<const short8*>(&AbufX[0][kb][lane * 8]);
            short8 a1 = *reinterpret_cast<const short8*>(&AbufX[1][kb][lane * 8]);
            A0 = __builtin_amdgcn_mfma_f32_16x16x32_bf16(a0, bw[kb], A0, 0, 0, 0);
            A1 = __builtin_amdgcn_mfma_f32_16x16x32_bf16(a1, bw[kb], A1, 0, 0, 0);
        }
    };
    auto gemm_h = [&](floatx4& A0, floatx4& A1) {   // B-frags bw[32..63]
#pragma unroll
        for (int kb = 0; kb < 32; ++kb) {
            short8 a0 = *reinterpret_cast<const short8*>(&AbufH[0][kb][lane * 8]);
            short8 a1 = *reinterpret_cast<const short8*>(&AbufH[1][kb][lane * 8]);
            A0 = __builtin_amdgcn_mfma_f32_16x16x32_bf16(a0, bw[32 + kb], A0, 0, 0, 0);
            A1 = __builtin_amdgcn_mfma_f32_16x16x32_bf16(a1, bw[32 + kb], A1, 0, 0, 0);
        }
    };
    // ------------------------------------------------------------------------

    // prologue: stage x(0)
    __syncthreads();
    stage_x_full(0);
    asm volatile("s_waitcnt lgkmcnt(0)" ::: "memory");
    __builtin_amdgcn_s_barrier();          // AbufX(0) ready

    for (int t = 0; t < 256; ++t) {
        // ---- 1. poll: all 8 sub-counters of this row group ----
        if (t > 0 && tid < 8) {
            int* sp = cnt + (r * 8 + tid) * 64;
            const int target = 8 * t;
            while (true) {
                int vv = __hip_atomic_load(sp, __ATOMIC_RELAXED,
                                           __HIP_MEMORY_SCOPE_AGENT);
                if (__ballot(vv >= target) == 0xFFull) break;
                __builtin_amdgcn_s_sleep(1);
            }
            if (!use_ph)   // fallback moves h through L2 -> must invalidate
                __builtin_amdgcn_fence(__ATOMIC_ACQUIRE, "agent");
        }
        __builtin_amdgcn_s_barrier();      // B1: release seen by all waves

        // ---- 2. issue h(t-1) IF loads to registers (no wait) ----
        uint4 hreg[16];
        if (t == 0) {
            stage_h0();
        } else if (use_ph) {
            // flat copy: pH parity slice (64 KiB for this row group) -> regs
            const char* bb = (const char*)pH + (size_t)(t & 1) * 262144 +
                             (size_t)r * 65536 + (tid >> 6) * 1024 + (tid & 63) * 16;
#pragma unroll
            for (int i = 0; i < 16; ++i)
                asm volatile("global_load_dwordx4 %0, %1, off sc0 sc1"
                             : "=v"(hreg[i]) : "v"(bb + (size_t)i * 4096) : "memory");
        } else {
            stage_h_out(t);
        }

        // ---- 3. x-GEMM runs under the in-flight h loads ----
        floatx4 acc0 = {0.f, 0.f, 0.f, 0.f}, acc1 = {0.f, 0.f, 0.f, 0.f};
        gemm_x(acc0, acc1);

        // ---- 4. drain h loads, write to LDS ----
        if (t > 0 && use_ph) {
            __builtin_amdgcn_sched_barrier(0);
            asm volatile("s_waitcnt vmcnt(0)" ::: "memory");
            __builtin_amdgcn_sched_barrier(0);
            unsigned short* ld = &AbufH[0][0][0] + (tid >> 6) * 512 + (tid & 63) * 8;
#pragma unroll
            for (int i = 0; i < 16; ++i)
                *reinterpret_cast<uint4*>(ld + i * 2048) = hreg[i];
        }
        __syncthreads();   // B2: AbufH ready

        // ---- 5. h-GEMM ----
        gemm_h(acc0, acc1);

        // ---- 6. epilogue: bias + activation into LDS ----
        // D layout (m89): row = quad*4 + rr, col = lane&15
#pragma unroll
        for (int rr = 0; rr < 4; ++rr) {
            float p0 = acc0[rr] + breg;
            float p1 = acc1[rr] + breg;
            float v0, v1;
            if (w == 2) { v0 = tanhf(p0); v1 = tanhf(p1); }
            else        { v0 = 1.f / (1.f + __expf(-p0)); v1 = 1.f / (1.f + __expf(-p1)); }
            g_lds[w][quad * 4 + rr][col]      = v0;
            g_lds[w][16 + quad * 4 + rr][col] = v1;
        }
        __syncthreads();   // B3: gates ready; AbufH reads done

        // ---- 7. cell update (fp32); hv/c kept in registers ----
        const int row0 = tid >> 4, cc = tid & 15;
        float hv0, hv1, cn0, cn1;
        {
            float iv = g_lds[0][row0][cc];
            float fv = g_lds[1][row0][cc];
            float gv = g_lds[2][row0][cc];
            float ov = g_lds[3][row0][cc];
            cn0 = fv * c_lds[row0][cc] + iv * gv;
            hv0 = ov * tanhf(cn0);
            c_lds[row0][cc]   = cn0;
            hbf_lds[row0][cc] = f2bf(hv0);
            int row1 = row0 + 16;
            iv = g_lds[0][row1][cc];
            fv = g_lds[1][row1][cc];
            gv = g_lds[2][row1][cc];
            ov = g_lds[3][row1][cc];
            cn1 = fv * c_lds[row1][cc] + iv * gv;
            hv1 = ov * tanhf(cn1);
            c_lds[row1][cc]   = cn1;
            hbf_lds[row1][cc] = f2bf(hv1);
        }
        __syncthreads();   // B4: hbf_lds ready for publish

        auto store_out = [&]() {
            const long hidbase = (long)t * 131072;
            const long m0 = 32 * r + row0, m1 = m0 + 16;
            out[hidbase + m0 * 1024 + j * 16 + cc] = hv0;
            out[hidbase + m1 * 1024 + j * 16 + cc] = hv1;
            if (t == 255) {
                out[HID_OFF + m0 * 1024 + j * 16 + cc] = hv0;
                out[HID_OFF + m1 * 1024 + j * 16 + cc] = hv1;
                out[CT_OFF  + m0 * 1024 + j * 16 + cc] = cn0;
                out[CT_OFF  + m1 * 1024 + j * 16 + cc] = cn1;
            }
        };

        if (!use_ph) store_out();   // fallback: out IS the exchange medium

        if (t < 255) {
            // ---- 8. publish h(t): coherent bf16 stores (wave 0) ----
            if (use_ph && tid < 64) {
                int ml = tid >> 1, cg = tid & 1;
                int m = 32 * r + ml, kcol = j * 16 + cg * 8;
                int frag  = (2 * r + (ml >> 4)) * 32 + (kcol >> 5);
                int lanep = (m & 15) + 16 * ((kcol & 31) >> 3);
                unsigned short* dst = pH + (size_t)((t & 1) ^ 1) * 131072 +
                                      (size_t)frag * 512 + lanep * 8;
                const unsigned long long* sv =
                    reinterpret_cast<const unsigned long long*>(&hbf_lds[ml][cg * 8]);
                unsigned long long* d64 = reinterpret_cast<unsigned long long*>(dst);
                __hip_atomic_store(d64, sv[0], __ATOMIC_RELAXED,
                                   __HIP_MEMORY_SCOPE_AGENT);
                __hip_atomic_store(d64 + 1, sv[1], __ATOMIC_RELAXED,
                                   __HIP_MEMORY_SCOPE_AGENT);
            }
            // ---- 9. arrive ----
            if (tid == 0) {
                if (use_ph) {
                    asm volatile("s_waitcnt vmcnt(0)" ::: "memory");
                    __hip_atomic_fetch_add(subp, 1, __ATOMIC_RELAXED,
                                           __HIP_MEMORY_SCOPE_AGENT);
                } else {
                    __hip_atomic_fetch_add(subp, 1, __ATOMIC_RELEASE,
                                           __HIP_MEMORY_SCOPE_AGENT);
                }
            }
        }

        if (use_ph) store_out();    // off the critical path

        // ---- 10. x prefetch for t+1 (overlaps straggler window) ----
        if (t < 255) stage_x_full(t + 1);
        asm volatile("s_waitcnt lgkmcnt(0)" ::: "memory");
        __builtin_amdgcn_s_barrier();   // tail: AbufX(t+1) ready; no vmcnt drain
    }
}

extern "C" void kernel_launch(void* const* d_in, const int* in_sizes, int n_in,
                              void* d_out, int out_size, void* d_ws, size_t ws_size,
                              hipStream_t stream) {
    (void)in_sizes; (void)n_in; (void)out_size;
    const float* x    = (const float*)d_in[0];
    const float* h0   = (const float*)d_in[1];
    const float* c0   = (const float*)d_in[2];
    const float* wih  = (const float*)d_in[3];
    const float* whh  = (const float*)d_in[4];
    const float* bias = (const float*)d_in[5];
    float* out = (float*)d_out;

    char* ws = (char*)d_ws;
    int* counters = (int*)ws;                 // 16 KiB counter region (spread lines)
    const size_t SZB = 2048ull * 4096 * 2;    // 16 MiB packed weights
    const size_t SZH = 2ull * 256 * 512 * 2;  // 512 KiB packed-h ping-pong
    const size_t SZX = 65536ull * 512 * 2;    // 64 MiB packed x

    size_t off = 16384;
    unsigned short* pB;
    if (ws_size >= off + SZB) {               // weights in ws
        pB = (unsigned short*)(ws + off); off += SZB;
    } else {                                  // tier D: weights in out tail
        // Safe with register-resident weights: loaded before step 0; out rows
        // [224,256) first written at t=224 (needs 224 sync rounds).
        pB = (unsigned short*)(out + WTAIL_F);
    }
    int use_ph = (ws_size >= off + SZH) ? 1 : 0;
    unsigned short* pH = use_ph ? (unsigned short*)(ws + off) : (unsigned short*)0;
    if (use_ph) off += SZH;
    int use_px = (ws_size >= off + SZX) ? 1 : 0;
    unsigned short* pX = use_px ? (unsigned short*)(ws + off) : (unsigned short*)0;

    hipMemsetAsync(ws, 0, 16384, stream);                     // barrier counters
    pack_w_kernel<<<4096, 256, 0, stream>>>(wih, whh, pB);
    if (use_px) pack_x_kernel<<<16384, 256, 0, stream>>>(x, pX);

    lstm_main<<<dim3(256), dim3(256), 0, stream>>>(
        x, h0, c0, bias, pB, pH, use_ph, pX, use_px, out, counters);
}